// Round 10
// baseline (42.422 us; speedup 1.0000x reference)
//
#include <hip/hip_runtime.h>
#include <math.h>

#define BATCH 128
#define HH 256
#define WW 256
#define HW (HH * WW)
#define HW4 (HW / 4)   // 16384 float4 per plane
#define NKPT 68

typedef float fx4 __attribute__((ext_vector_type(4)));

__device__ inline double wave_sum64(double v) {
#pragma unroll
    for (int off = 32; off > 0; off >>= 1) v += __shfl_xor(v, off);
    return v;
}

// ---------------------------------------------------------------------------
// Kernel A: per-batch similarity transform. One wave per batch, 128 blocks.
// Lane-parallel gather + one butterfly-reduction pass; lane 0 computes
// R = polar(Hm^T) via det-scaled Newton iteration (quadratically convergent
// to the SVD's V U^T). Verified R9: absmax 0.03125.
// ---------------------------------------------------------------------------
__global__ __launch_bounds__(64, 1) void tform_kernel(
    const float* __restrict__ Offset, const float* __restrict__ Posmap,
    const float* __restrict__ meanp, const int* __restrict__ uv,
    float* __restrict__ RT) {
    const int b = blockIdx.x;
    const int lane = threadIdx.x;
    const float* offb = Offset + (size_t)b * 3 * HW;
    const float* dstb = Posmap + (size_t)b * 3 * HW;
    const bool has1 = lane < (NKPT - 64);

    double s0[3], d0[3], s1[3] = {0, 0, 0}, d1[3] = {0, 0, 0};
    {
        const int q0 = uv[lane * 2 + 0] * WW + uv[lane * 2 + 1];
#pragma unroll
        for (int i = 0; i < 3; i++) {
            s0[i] = (double)offb[(size_t)i * HW + q0] * 6.0 +
                    (double)meanp[(size_t)i * HW + q0];
            d0[i] = (double)dstb[(size_t)i * HW + q0];
        }
        if (has1) {
            const int k1 = lane + 64;
            const int q1 = uv[k1 * 2 + 0] * WW + uv[k1 * 2 + 1];
#pragma unroll
            for (int i = 0; i < 3; i++) {
                s1[i] = (double)offb[(size_t)i * HW + q1] * 6.0 +
                        (double)meanp[(size_t)i * HW + q1];
                d1[i] = (double)dstb[(size_t)i * HW + q1];
            }
        }
    }

    double s33[3], d33[3];
#pragma unroll
    for (int i = 0; i < 3; i++) {
        s33[i] = __shfl(s0[i], 33);
        d33[i] = __shfl(d0[i], 33);
    }

    double ns0 = 0, nd0 = 0, ns1 = 0, nd1 = 0;
    double ssum[3], dsum[3], P[3][3];
#pragma unroll
    for (int i = 0; i < 3; i++) {
        double es = s0[i] - s33[i], ed = d0[i] - d33[i];
        ns0 += es * es;
        nd0 += ed * ed;
        es = s1[i] - s33[i];
        ed = d1[i] - d33[i];
        ns1 += es * es;
        nd1 += ed * ed;
        ssum[i] = s0[i] + s1[i];
        dsum[i] = d0[i] + d1[i];
#pragma unroll
        for (int j = 0; j < 3; j++) P[i][j] = s0[i] * d0[j] + s1[i] * d1[j];
    }
    double sd1p = sqrt(ns0) + (has1 ? sqrt(ns1) : 0.0);
    double sd2p = sqrt(nd0) + (has1 ? sqrt(nd1) : 0.0);

    const double sd1 = wave_sum64(sd1p);
    const double sd2 = wave_sum64(sd2p);
#pragma unroll
    for (int i = 0; i < 3; i++) {
        ssum[i] = wave_sum64(ssum[i]);
        dsum[i] = wave_sum64(dsum[i]);
    }
#pragma unroll
    for (int i = 0; i < 3; i++)
#pragma unroll
        for (int j = 0; j < 3; j++) P[i][j] = wave_sum64(P[i][j]);

    if (lane != 0) return;

    const double s = sd2 / sd1;
    double sbar[3], dbar[3];
#pragma unroll
    for (int i = 0; i < 3; i++) {
        sbar[i] = ssum[i] / NKPT;
        dbar[i] = dsum[i] / NKPT;
    }
    double Hm[3][3];
#pragma unroll
    for (int i = 0; i < 3; i++)
#pragma unroll
        for (int j = 0; j < 3; j++)
            Hm[i][j] = P[i][j] - (double)NKPT * sbar[i] * dbar[j];

    // X = Hm^T ; Newton polar iteration with determinant scaling.
    double X[3][3];
#pragma unroll
    for (int i = 0; i < 3; i++)
#pragma unroll
        for (int j = 0; j < 3; j++) X[i][j] = Hm[j][i];

#pragma unroll
    for (int it = 0; it < 9; ++it) {
        double C[3][3];
        C[0][0] = X[1][1] * X[2][2] - X[1][2] * X[2][1];
        C[0][1] = X[1][2] * X[2][0] - X[1][0] * X[2][2];
        C[0][2] = X[1][0] * X[2][1] - X[1][1] * X[2][0];
        C[1][0] = X[0][2] * X[2][1] - X[0][1] * X[2][2];
        C[1][1] = X[0][0] * X[2][2] - X[0][2] * X[2][0];
        C[1][2] = X[0][1] * X[2][0] - X[0][0] * X[2][1];
        C[2][0] = X[0][1] * X[1][2] - X[0][2] * X[1][1];
        C[2][1] = X[0][2] * X[1][0] - X[0][0] * X[1][2];
        C[2][2] = X[0][0] * X[1][1] - X[0][1] * X[1][0];
        double det =
            X[0][0] * C[0][0] + X[0][1] * C[0][1] + X[0][2] * C[0][2];
        double ad = fabs(det);
        if (ad < 1e-250) ad = 1e-250;
        const double mu = 1.0 / cbrt(ad);
        const double inv = 1.0 / (mu * det);
#pragma unroll
        for (int i = 0; i < 3; i++)
#pragma unroll
            for (int j = 0; j < 3; j++)
                X[i][j] = 0.5 * (mu * X[i][j] + C[i][j] * inv);
    }

    float* rt = RT + b * 12;
    for (int j = 0; j < 3; j++) {
        for (int i = 0; i < 3; i++) rt[j * 3 + i] = (float)(X[j][i] * s);
        double tj = dbar[j];
        for (int i = 0; i < 3; i++) tj -= s * sbar[i] * X[j][i];
        rt[9 + j] = (float)tj;
    }
}

// ---------------------------------------------------------------------------
// Kernel B: out[b,j,h,w] = sum_i (Offset[b,i,h,w]*6 + mean[i,h,w]) * Rs[j][i]
//                          + t[j]
// 2048 blocks, 4 chunks per block in two pairs. All 24 loads issued in
// program order up front (A-HBM, B-HBM, A-mean, B-mean) so both computes'
// waitcnts are satisfied before any store issues; NT stores fire-and-forget.
// ---------------------------------------------------------------------------
__global__ __launch_bounds__(256, 4) void apply_kernel(
    const fx4* __restrict__ Off, const fx4* __restrict__ Mean,
    const float* __restrict__ RT, fx4* __restrict__ Out) {
    const int QUADS = HW4 / 1024;  // 16 chunk-quads per batch
    const int b = blockIdx.x / QUADS;
    const int w = blockIdx.x % QUADS;
    const int p0 = w * 1024 + threadIdx.x;
    const int p1 = p0 + 256;
    const int p2 = p0 + 512;
    const int p3 = p0 + 768;
    const size_t base = (size_t)b * 3 * HW4;

    // --- all loads up front: A-HBM, B-HBM, A-mean, B-mean ---
    fx4 a00 = Off[base + p0];
    fx4 a01 = Off[base + HW4 + p0];
    fx4 a02 = Off[base + 2 * HW4 + p0];
    fx4 a10 = Off[base + p1];
    fx4 a11 = Off[base + HW4 + p1];
    fx4 a12 = Off[base + 2 * HW4 + p1];
    fx4 b00 = Off[base + p2];
    fx4 b01 = Off[base + HW4 + p2];
    fx4 b02 = Off[base + 2 * HW4 + p2];
    fx4 b10 = Off[base + p3];
    fx4 b11 = Off[base + HW4 + p3];
    fx4 b12 = Off[base + 2 * HW4 + p3];
    fx4 ma00 = Mean[p0];
    fx4 ma01 = Mean[HW4 + p0];
    fx4 ma02 = Mean[2 * HW4 + p0];
    fx4 ma10 = Mean[p1];
    fx4 ma11 = Mean[HW4 + p1];
    fx4 ma12 = Mean[2 * HW4 + p1];
    fx4 mb00 = Mean[p2];
    fx4 mb01 = Mean[HW4 + p2];
    fx4 mb02 = Mean[2 * HW4 + p2];
    fx4 mb10 = Mean[p3];
    fx4 mb11 = Mean[HW4 + p3];
    fx4 mb12 = Mean[2 * HW4 + p3];

    const float* rt = RT + b * 12;
    const float r00 = rt[0], r01 = rt[1], r02 = rt[2];
    const float r10 = rt[3], r11 = rt[4], r12 = rt[5];
    const float r20 = rt[6], r21 = rt[7], r22 = rt[8];
    const float t0 = rt[9], t1 = rt[10], t2 = rt[11];

#define XFORM(i0, i1, i2, mm0, mm1, mm2, oo0, oo1, oo2)               \
    {                                                                 \
        fx4 q0, q1, q2;                                               \
        _Pragma("unroll") for (int e = 0; e < 4; e++) {               \
            float x0 = fmaf(i0[e], 6.0f, mm0[e]);                     \
            float x1 = fmaf(i1[e], 6.0f, mm1[e]);                     \
            float x2 = fmaf(i2[e], 6.0f, mm2[e]);                     \
            q0[e] = fmaf(x0, r00, fmaf(x1, r01, fmaf(x2, r02, t0)));  \
            q1[e] = fmaf(x0, r10, fmaf(x1, r11, fmaf(x2, r12, t1)));  \
            q2[e] = fmaf(x0, r20, fmaf(x1, r21, fmaf(x2, r22, t2)));  \
        }                                                             \
        __builtin_nontemporal_store(q0, &Out[base + (oo0)]);          \
        __builtin_nontemporal_store(q1, &Out[base + HW4 + (oo1)]);    \
        __builtin_nontemporal_store(q2, &Out[base + 2 * HW4 + (oo2)]);\
    }

    XFORM(a00, a01, a02, ma00, ma01, ma02, p0, p0, p0)
    XFORM(a10, a11, a12, ma10, ma11, ma12, p1, p1, p1)
    XFORM(b00, b01, b02, mb00, mb01, mb02, p2, p2, p2)
    XFORM(b10, b11, b12, mb10, mb11, mb12, p3, p3, p3)
#undef XFORM
}

extern "C" void kernel_launch(void* const* d_in, const int* in_sizes, int n_in,
                              void* d_out, int out_size, void* d_ws,
                              size_t ws_size, hipStream_t stream) {
    const float* Offset = (const float*)d_in[0];
    const float* Posmap = (const float*)d_in[1];
    const float* meanp = (const float*)d_in[2];
    const int* uv = (const int*)d_in[3];
    float* out = (float*)d_out;
    float* RT = (float*)d_ws;  // 128 * 12 floats

    tform_kernel<<<BATCH, 64, 0, stream>>>(Offset, Posmap, meanp, uv, RT);
    apply_kernel<<<BATCH * (HW4 / 1024), 256, 0, stream>>>(
        (const fx4*)Offset, (const fx4*)meanp, RT, (fx4*)out);
}

// Round 11
// 42.260 us; speedup vs baseline: 1.0038x; 1.0038x over previous
//
#include <hip/hip_runtime.h>
#include <math.h>

#define BATCH 128
#define HH 256
#define WW 256
#define HW (HH * WW)
#define HW4 (HW / 4)   // 16384 float4 per plane
#define NKPT 68
#define ITERS 4        // chunks per block
#define BPB 16         // blocks per batch (16*4 = 64 chunks)

typedef float fx4 __attribute__((ext_vector_type(4)));

__device__ inline double wave_sum64(double v) {
#pragma unroll
    for (int off = 32; off > 0; off >>= 1) v += __shfl_xor(v, off);
    return v;
}

// ---------------------------------------------------------------------------
// Kernel A: per-batch similarity transform (verified R9: absmax 0.03125).
// One wave per batch. Lane-parallel gather + one butterfly-reduction pass;
// lane 0 computes R = polar(Hm^T) via det-scaled Newton iteration.
// ---------------------------------------------------------------------------
__global__ __launch_bounds__(64, 1) void tform_kernel(
    const float* __restrict__ Offset, const float* __restrict__ Posmap,
    const float* __restrict__ meanp, const int* __restrict__ uv,
    float* __restrict__ RT) {
    const int b = blockIdx.x;
    const int lane = threadIdx.x;
    const float* offb = Offset + (size_t)b * 3 * HW;
    const float* dstb = Posmap + (size_t)b * 3 * HW;
    const bool has1 = lane < (NKPT - 64);

    double s0[3], d0[3], s1[3] = {0, 0, 0}, d1[3] = {0, 0, 0};
    {
        const int q0 = uv[lane * 2 + 0] * WW + uv[lane * 2 + 1];
#pragma unroll
        for (int i = 0; i < 3; i++) {
            s0[i] = (double)offb[(size_t)i * HW + q0] * 6.0 +
                    (double)meanp[(size_t)i * HW + q0];
            d0[i] = (double)dstb[(size_t)i * HW + q0];
        }
        if (has1) {
            const int k1 = lane + 64;
            const int q1 = uv[k1 * 2 + 0] * WW + uv[k1 * 2 + 1];
#pragma unroll
            for (int i = 0; i < 3; i++) {
                s1[i] = (double)offb[(size_t)i * HW + q1] * 6.0 +
                        (double)meanp[(size_t)i * HW + q1];
                d1[i] = (double)dstb[(size_t)i * HW + q1];
            }
        }
    }

    double s33[3], d33[3];
#pragma unroll
    for (int i = 0; i < 3; i++) {
        s33[i] = __shfl(s0[i], 33);
        d33[i] = __shfl(d0[i], 33);
    }

    double ns0 = 0, nd0 = 0, ns1 = 0, nd1 = 0;
    double ssum[3], dsum[3], P[3][3];
#pragma unroll
    for (int i = 0; i < 3; i++) {
        double es = s0[i] - s33[i], ed = d0[i] - d33[i];
        ns0 += es * es;
        nd0 += ed * ed;
        es = s1[i] - s33[i];
        ed = d1[i] - d33[i];
        ns1 += es * es;
        nd1 += ed * ed;
        ssum[i] = s0[i] + s1[i];
        dsum[i] = d0[i] + d1[i];
#pragma unroll
        for (int j = 0; j < 3; j++) P[i][j] = s0[i] * d0[j] + s1[i] * d1[j];
    }
    double sd1p = sqrt(ns0) + (has1 ? sqrt(ns1) : 0.0);
    double sd2p = sqrt(nd0) + (has1 ? sqrt(nd1) : 0.0);

    const double sd1 = wave_sum64(sd1p);
    const double sd2 = wave_sum64(sd2p);
#pragma unroll
    for (int i = 0; i < 3; i++) {
        ssum[i] = wave_sum64(ssum[i]);
        dsum[i] = wave_sum64(dsum[i]);
    }
#pragma unroll
    for (int i = 0; i < 3; i++)
#pragma unroll
        for (int j = 0; j < 3; j++) P[i][j] = wave_sum64(P[i][j]);

    if (lane != 0) return;

    const double s = sd2 / sd1;
    double sbar[3], dbar[3];
#pragma unroll
    for (int i = 0; i < 3; i++) {
        sbar[i] = ssum[i] / NKPT;
        dbar[i] = dsum[i] / NKPT;
    }
    double Hm[3][3];
#pragma unroll
    for (int i = 0; i < 3; i++)
#pragma unroll
        for (int j = 0; j < 3; j++)
            Hm[i][j] = P[i][j] - (double)NKPT * sbar[i] * dbar[j];

    double X[3][3];
#pragma unroll
    for (int i = 0; i < 3; i++)
#pragma unroll
        for (int j = 0; j < 3; j++) X[i][j] = Hm[j][i];

#pragma unroll
    for (int it = 0; it < 9; ++it) {
        double C[3][3];
        C[0][0] = X[1][1] * X[2][2] - X[1][2] * X[2][1];
        C[0][1] = X[1][2] * X[2][0] - X[1][0] * X[2][2];
        C[0][2] = X[1][0] * X[2][1] - X[1][1] * X[2][0];
        C[1][0] = X[0][2] * X[2][1] - X[0][1] * X[2][2];
        C[1][1] = X[0][0] * X[2][2] - X[0][2] * X[2][0];
        C[1][2] = X[0][1] * X[2][0] - X[0][0] * X[2][1];
        C[2][0] = X[0][1] * X[1][2] - X[0][2] * X[1][1];
        C[2][1] = X[0][2] * X[1][0] - X[0][0] * X[1][2];
        C[2][2] = X[0][0] * X[1][1] - X[0][1] * X[1][0];
        double det =
            X[0][0] * C[0][0] + X[0][1] * C[0][1] + X[0][2] * C[0][2];
        double ad = fabs(det);
        if (ad < 1e-250) ad = 1e-250;
        const double mu = 1.0 / cbrt(ad);
        const double inv = 1.0 / (mu * det);
#pragma unroll
        for (int i = 0; i < 3; i++)
#pragma unroll
            for (int j = 0; j < 3; j++)
                X[i][j] = 0.5 * (mu * X[i][j] + C[i][j] * inv);
    }

    float* rt = RT + b * 12;
    for (int j = 0; j < 3; j++) {
        for (int i = 0; i < 3; i++) rt[j * 3 + i] = (float)(X[j][i] * s);
        double tj = dbar[j];
        for (int i = 0; i < 3; i++) tj -= s * sbar[i] * X[j][i];
        rt[9 + j] = (float)tj;
    }
}

// ---------------------------------------------------------------------------
// Kernel B: 2048 persistent-ish blocks, 4 chunks each, 2-stage register
// pipeline. Issue order per iteration:
//   [all 6 loads of iter i+1 (Offset HBM + Mean L2)] -> [compute iter i,
//   whose loads were issued one stage earlier => wait leaves 9 newer vmem
//   ops outstanding] -> [3 NT stores of iter i].
// The wait for iter i's data never drains the i+1 prefetch nor the stores
// (vmcnt in-order retirement). This fixes R7's bug (Mean was loaded AFTER
// the prefetch there, forcing vmcnt(0) each iteration).
// ---------------------------------------------------------------------------
__global__ __launch_bounds__(256, 4) void apply_kernel(
    const fx4* __restrict__ Off, const fx4* __restrict__ Mean,
    const float* __restrict__ RT, fx4* __restrict__ Out) {
    const int blk = blockIdx.x;
    const int tid = threadIdx.x;
    const int b = blk / BPB;
    const int cstart = (blk % BPB) * ITERS;
    const size_t base = (size_t)b * 3 * HW4;

    const float* rt = RT + b * 12;
    const float r00 = rt[0], r01 = rt[1], r02 = rt[2];
    const float r10 = rt[3], r11 = rt[4], r12 = rt[5];
    const float r20 = rt[6], r21 = rt[7], r22 = rt[8];
    const float t0 = rt[9], t1 = rt[10], t2 = rt[11];

    int p = cstart * 256 + tid;

    // Prologue: stage 0 loads.
    fx4 c0 = Off[base + p];
    fx4 c1 = Off[base + HW4 + p];
    fx4 c2 = Off[base + 2 * HW4 + p];
    fx4 cm0 = Mean[p];
    fx4 cm1 = Mean[HW4 + p];
    fx4 cm2 = Mean[2 * HW4 + p];

#pragma unroll
    for (int it = 0; it < ITERS; ++it) {
        fx4 n0, n1, n2, nm0, nm1, nm2;
        if (it < ITERS - 1) {
            const int pn = p + 256;
            n0 = Off[base + pn];
            n1 = Off[base + HW4 + pn];
            n2 = Off[base + 2 * HW4 + pn];
            nm0 = Mean[pn];
            nm1 = Mean[HW4 + pn];
            nm2 = Mean[2 * HW4 + pn];
        }

        fx4 y0, y1, y2;
#pragma unroll
        for (int e = 0; e < 4; e++) {
            float x0 = fmaf(c0[e], 6.0f, cm0[e]);
            float x1 = fmaf(c1[e], 6.0f, cm1[e]);
            float x2 = fmaf(c2[e], 6.0f, cm2[e]);
            y0[e] = fmaf(x0, r00, fmaf(x1, r01, fmaf(x2, r02, t0)));
            y1[e] = fmaf(x0, r10, fmaf(x1, r11, fmaf(x2, r12, t1)));
            y2[e] = fmaf(x0, r20, fmaf(x1, r21, fmaf(x2, r22, t2)));
        }
        __builtin_nontemporal_store(y0, &Out[base + p]);
        __builtin_nontemporal_store(y1, &Out[base + HW4 + p]);
        __builtin_nontemporal_store(y2, &Out[base + 2 * HW4 + p]);

        if (it < ITERS - 1) {
            c0 = n0;
            c1 = n1;
            c2 = n2;
            cm0 = nm0;
            cm1 = nm1;
            cm2 = nm2;
            p += 256;
        }
    }
}

extern "C" void kernel_launch(void* const* d_in, const int* in_sizes, int n_in,
                              void* d_out, int out_size, void* d_ws,
                              size_t ws_size, hipStream_t stream) {
    const float* Offset = (const float*)d_in[0];
    const float* Posmap = (const float*)d_in[1];
    const float* meanp = (const float*)d_in[2];
    const int* uv = (const int*)d_in[3];
    float* out = (float*)d_out;
    float* RT = (float*)d_ws;  // 128 * 12 floats

    tform_kernel<<<BATCH, 64, 0, stream>>>(Offset, Posmap, meanp, uv, RT);
    apply_kernel<<<BATCH * BPB, 256, 0, stream>>>(
        (const fx4*)Offset, (const fx4*)meanp, RT, (fx4*)out);
}